// Round 10
// baseline (50.424 us; speedup 1.0000x reference)
//
#include <hip/hip_runtime.h>
#include <hip/hip_bf16.h>

// out[i][j] = (x@beta)[i][j] - 0.1*y[i][j]*||beta[:,j]||_1
//             + (4096*rowsum(W2)[j] + bias2[j] + bias_lin[j])
// M=4096, K=2048, N=1024. adv==1 always.
//
// Pipeline (all atomic-free):
//   pre_kernel  grid 1792 (round-8, ~HBM-roofline): x->bf16; beta->bf16
//               beta^T + L1 partials via shfl; W2 row sums.
//   gemm_kernel grid 512 x 1024 threads (16 waves = 2k x 4m x 2n; K-split
//               within block, wave tile 32x32): BM=128 BN=64 BK=64, 3 LDS
//               buffers, lookahead-2 global_load_lds, per-wave counted vmcnt,
//               zero-conflict XOR-swizzled LDS, end-of-kernel K-half merge via
//               LDS, fused epilogue. 2 blocks/CU x 16 waves = 32 waves/CU.

typedef float    f32x4  __attribute__((ext_vector_type(4)));
typedef unsigned u32x2  __attribute__((ext_vector_type(2)));
typedef unsigned u32x4  __attribute__((ext_vector_type(4)));
typedef short    bf16x8 __attribute__((ext_vector_type(8)));

constexpr int M = 4096;
constexpr int N = 1024;
constexpr int K = 2048;
constexpr int NHID = 4096;

__device__ __forceinline__ unsigned pkbf(float a, float b) {
    __hip_bfloat162 h = __float22bfloat162_rn(make_float2(a, b));
    unsigned u; __builtin_memcpy(&u, &h, 4); return u;
}

__device__ __forceinline__ void gll16(const void* g, void* l) {
    __builtin_amdgcn_global_load_lds(
        (const __attribute__((address_space(1))) void*)g,
        (__attribute__((address_space(3))) void*)l, 16, 0, 0);
}

// =================== pre (unchanged from round 8) ===========================
__global__ void __launch_bounds__(256) pre_kernel(
    const float* __restrict__ x, const float* __restrict__ beta,
    const float* __restrict__ W2,
    short* __restrict__ xb, short* __restrict__ bt,
    float* __restrict__ partials,   // [32][1024]
    float* __restrict__ wsum) {     // [1024]
    __shared__ float tls[64 * 68];
    const int bx = blockIdx.x, tid = threadIdx.x;
    if (bx < 1024) {
        const f32x4* x4 = (const f32x4*)x;
        u32x2* o2 = (u32x2*)xb;
        #pragma unroll
        for (int it = 0; it < 8; ++it) {
            const int i = (it * 1024 + bx) * 256 + tid;
            f32x4 v = x4[i];
            u32x2 p = { pkbf(v[0], v[1]), pkbf(v[2], v[3]) };
            o2[i] = p;
        }
    } else if (bx < 1536) {
        const int tile = bx - 1024, tk = tile & 31, tn = tile >> 5;
        {
            const int r = tid >> 2, c0 = (tid & 3) * 16;
            const float* src = beta + (size_t)(tk * 64 + r) * N + tn * 64 + c0;
            #pragma unroll
            for (int j = 0; j < 4; ++j)
                *(f32x4*)&tls[r * 68 + c0 + j * 4] = *(const f32x4*)(src + j * 4);
        }
        __syncthreads();
        {
            const int n = tid >> 2, k0 = (tid & 3) * 16;
            float s = 0.f;
            unsigned pk[8];
            #pragma unroll
            for (int j = 0; j < 8; ++j) {
                float a = tls[(k0 + 2 * j) * 68 + n];
                float b = tls[(k0 + 2 * j + 1) * 68 + n];
                s += fabsf(a) + fabsf(b);
                pk[j] = pkbf(a, b);
            }
            s += __shfl_xor(s, 1);
            s += __shfl_xor(s, 2);
            if ((tid & 3) == 0) partials[tk * 1024 + tn * 64 + n] = s;
            u32x4* dst = (u32x4*)(bt + (size_t)(tn * 64 + n) * K + tk * 64 + k0);
            u32x4 p0 = { pk[0], pk[1], pk[2], pk[3] };
            u32x4 p1 = { pk[4], pk[5], pk[6], pk[7] };
            dst[0] = p0; dst[1] = p1;
        }
    } else {
        const int b = bx - 1536;
        const int wv = tid >> 6, lane = tid & 63;
        const int row = b * 4 + wv;
        const f32x4* w4 = (const f32x4*)(W2 + (size_t)row * NHID);
        float acc = 0.f;
        #pragma unroll
        for (int i = 0; i < 16; ++i) {
            f32x4 v = w4[i * 64 + lane];
            acc += v[0] + v[1] + v[2] + v[3];
        }
        #pragma unroll
        for (int off = 32; off; off >>= 1) acc += __shfl_down(acc, off);
        if (lane == 0) wsum[row] = acc;
    }
}

// =================== main GEMM: 16 waves, K-split, 3-buf ====================
// BM=128 x BN=64, BK=64. 16 waves = 2k x 4m x 2n; wave tile 32x32 computes
// its K-half (wk*32..wk*32+31) of each tile. Grid 512 -> 2 blocks/CU =
// 32 waves/CU (8/SIMD; requires VGPR <= 64). One barrier per K-step,
// per-wave counted vmcnt BEFORE barrier publishes staging completion.
// XOR swizzle: LDS slot (row, s) holds global chunk s^(row&7); reads XOR back.
// End: wk=1 waves dump acc to (free) staging LDS; wk=0 merges + epilogue.
constexpr int BM = 128, BN = 64, BK = 64;
constexpr int NT  = K / BK;          // 32
constexpr int ASZ = BM * BK;         // 8192 shorts (16KB)
constexpr int BSZ = BN * BK;         // 4096 shorts (8KB)

__global__ void __launch_bounds__(1024, 8) gemm_kernel(
    const short* __restrict__ xb, const short* __restrict__ bt,
    const float* __restrict__ y,
    const float* __restrict__ partials, const float* __restrict__ wsum,
    const float* __restrict__ bias_lin, const float* __restrict__ bias2,
    float* __restrict__ out) {
    __shared__ __align__(16) short Al[3 * ASZ];   // 48KB (also merge scratch)
    __shared__ __align__(16) short Bl[3 * BSZ];   // 24KB

    const int tid = threadIdx.x, lane = tid & 63, w = tid >> 6;   // w: 0..15
    const int wk = w >> 3, wm = (w >> 1) & 3, wn = w & 1;         // 2k x 4m x 2n
    // XCD swizzle: xcd c gets 16mb x 4nb contiguous region (512 = 8 x 64)
    const int c = blockIdx.x & 7, local = blockIdx.x >> 3;
    const int mb = ((c & 1) << 4) + (local >> 2);
    const int nb = ((c >> 1) << 2) + (local & 3);
    const int brow = mb * BM, bcol = nb * BN;

    // staging: per-lane pre-swizzled global source, linear LDS dest.
    // A: all 1024 threads, 1 inst: row = tid>>3 (0..127), slot = tid&7.
    // B: threads 0..511 (waves 0..7), 1 inst: row = tid>>3 (0..63).
    const int srow = tid >> 3, sslot = tid & 7;
    const int schk = sslot ^ (srow & 7);
    const short* asrc = xb + (size_t)(brow + srow) * K + schk * 8;
    const short* bsrc = bt + (size_t)(bcol + srow) * K + schk * 8;  // valid w<8
    short* Abase = &Al[w * 512];             // wave-uniform, +buf*ASZ
    short* Bbase = &Bl[w * 512];             // wave-uniform (w<8), +buf*BSZ

    f32x4 acc[2][2];
    #pragma unroll
    for (int m = 0; m < 2; ++m)
        #pragma unroll
        for (int n = 0; n < 2; ++n) acc[m][n] = (f32x4)0.f;

    auto STAGE = [&](int buf, int t) {
        gll16(asrc + t * BK, Abase + buf * ASZ);
        if (w < 8) gll16(bsrc + t * BK, Bbase + buf * BSZ);
    };

    // fragment LDS offsets (shorts); wave reads only its K-half (chunks wk*4..+3)
    const int r = lane & 15, q = lane >> 4;
    int aoff[2], boff[2];
    #pragma unroll
    for (int m = 0; m < 2; ++m) {
        const int row = wm * 32 + m * 16 + r;
        const int ch = (wk * 4 + q) ^ (r & 7);
        aoff[m] = row * 64 + ch * 8;
    }
    #pragma unroll
    for (int n = 0; n < 2; ++n) {
        const int row = wn * 32 + n * 16 + r;
        const int ch = (wk * 4 + q) ^ (r & 7);
        boff[n] = row * 64 + ch * 8;
    }

    auto COMPUTE = [&](int buf) {
        const short* A = &Al[buf * ASZ];
        const short* B = &Bl[buf * BSZ];
        bf16x8 af[2], bfr[2];
        #pragma unroll
        for (int m = 0; m < 2; ++m) af[m] = *(const bf16x8*)&A[aoff[m]];
        #pragma unroll
        for (int n = 0; n < 2; ++n) bfr[n] = *(const bf16x8*)&B[boff[n]];
        #pragma unroll
        for (int m = 0; m < 2; ++m)
            #pragma unroll
            for (int n = 0; n < 2; ++n)
                acc[m][n] = __builtin_amdgcn_mfma_f32_16x16x32_bf16(
                    af[m], bfr[n], acc[m][n], 0, 0, 0);
    };

    STAGE(0, 0);
    STAGE(1, 1);
    for (int t = 0; t < NT; ++t) {
        // wait own tile-t loads; barrier publishes everyone's completion.
        if (t < NT - 1) {
            if (w < 8) { asm volatile("s_waitcnt vmcnt(2)" ::: "memory"); }
            else       { asm volatile("s_waitcnt vmcnt(1)" ::: "memory"); }
        } else {
            asm volatile("s_waitcnt vmcnt(0)" ::: "memory");
        }
        __builtin_amdgcn_s_barrier();
        __builtin_amdgcn_sched_barrier(0);
        if (t + 2 < NT) STAGE((t + 2) % 3, t + 2);
        COMPUTE(t % 3);
    }

    // ---- merge K-halves: wk=1 dumps acc into Al (free now), wk=0 adds ----
    __syncthreads();
    float* mrg = (float*)Al;   // 8 waves x 4 frags x 256 floats = 32KB <= 48KB
    if (wk == 1) {
        #pragma unroll
        for (int m = 0; m < 2; ++m)
            #pragma unroll
            for (int n = 0; n < 2; ++n)
                *(f32x4*)&mrg[(((w - 8) * 4 + m * 2 + n) * 256) + lane * 4] =
                    acc[m][n];
    }
    __syncthreads();
    if (wk == 0) {
        #pragma unroll
        for (int m = 0; m < 2; ++m)
            #pragma unroll
            for (int n = 0; n < 2; ++n) {
                f32x4 v = *(const f32x4*)&mrg[((w * 4 + m * 2 + n) * 256) + lane * 4];
                acc[m][n] += v;
            }
        // ---- epilogue: out = acc + cterm[col] - 0.1*bnorm[col]*y ----
        #pragma unroll
        for (int n = 0; n < 2; ++n) {
            const int gc = bcol + wn * 32 + n * 16 + r;
            float bsum = 0.f;
            #pragma unroll 8
            for (int tk = 0; tk < 32; ++tk) bsum += partials[tk * 1024 + gc];
            const float be = 0.1f * bsum;
            const float ct = bias_lin[gc] + bias2[gc] + (float)NHID * wsum[gc];
            #pragma unroll
            for (int m = 0; m < 2; ++m) {
                const int gr0 = brow + wm * 32 + m * 16 + q * 4;
                f32x4 v = acc[m][n];
                #pragma unroll
                for (int rr = 0; rr < 4; ++rr) {
                    size_t idx = (size_t)(gr0 + rr) * N + gc;
                    out[idx] = v[rr] + ct - be * y[idx];
                }
            }
        }
    }
}

extern "C" void kernel_launch(void* const* d_in, const int* in_sizes, int n_in,
                              void* d_out, int out_size, void* d_ws, size_t ws_size,
                              hipStream_t stream) {
    const float* x        = (const float*)d_in[0];
    const float* y        = (const float*)d_in[1];
    const float* beta     = (const float*)d_in[2];
    const float* bias_lin = (const float*)d_in[3];
    const float* W2       = (const float*)d_in[5];
    const float* bias2    = (const float*)d_in[7];
    float* out = (float*)d_out;

    float* partials = (float*)d_ws;                        // [32][1024]
    float* wsum     = partials + 32 * 1024;                // [1024]
    short* xb       = (short*)(wsum + 1024);               // [M][K] bf16
    short* bts      = xb + (size_t)M * K;                  // [N][K] bf16 (beta^T)

    pre_kernel<<<1792, 256, 0, stream>>>(x, beta, W2, xb, bts, partials, wsum);
    gemm_kernel<<<512, 1024, 0, stream>>>(xb, bts, y, partials, wsum,
                                          bias_lin, bias2, out);
}